// Round 1
// baseline (454.732 us; speedup 1.0000x reference)
//
#include <hip/hip_runtime.h>
#include <hip/hip_bf16.h>

// Problem constants
#define M_TOT   8192      // B*N tokens
#define D_IN    4096
#define D_OUT   4096
#define N_E     8
#define N_R     16
#define D_ATT   128
#define ER      128       // N_E*N_R
#define CATN    384       // 2*D_ATT + ER

typedef __attribute__((ext_vector_type(8))) __bf16 bf16x8;
typedef __attribute__((ext_vector_type(4))) float  f32x4;

__device__ __forceinline__ ushort f2bf(float f) {
  union { float f; unsigned u; } v; v.f = f;
  unsigned r = (v.u + 0x7fffu + ((v.u >> 16) & 1u)) >> 16;
  return (ushort)r;
}

// ---- fp32 -> bf16 conversion, 4 elems/thread ----
__global__ void f2bf4_kernel(const float* __restrict__ in, ushort* __restrict__ out, long n4) {
  long i = blockIdx.x * (long)blockDim.x + threadIdx.x;
  if (i >= n4) return;
  const float4 a = reinterpret_cast<const float4*>(in)[i];
  ushort4 r; r.x = f2bf(a.x); r.y = f2bf(a.y); r.z = f2bf(a.z); r.w = f2bf(a.w);
  reinterpret_cast<ushort4*>(out)[i] = r;
}

// ---- Cat rows 256..383: Cat[256+j][d] = experts_A[e][d][r], j=e*16+r ----
__global__ void prep_catA_kernel(const float* __restrict__ expA, ushort* __restrict__ cat) {
  int idx = blockIdx.x * 256 + threadIdx.x;       // over 128*4096
  int j = idx >> 12, d = idx & 4095;
  int e = j >> 4, r = j & 15;
  cat[(size_t)(2 * D_ATT + j) * D_IN + d] = f2bf(expA[((size_t)e * D_IN + d) * N_R + r]);
}

// ---- Bt[o][j] = experts_B_flat[j][o]  (so MoE GEMM is B^T-form like main) ----
__global__ void prep_bt_kernel(const float* __restrict__ expB, ushort* __restrict__ bt) {
  int idx = blockIdx.x * 256 + threadIdx.x;       // over 128*4096
  int j = idx >> 12, o = idx & 4095;              // coalesced read of expB row j
  bt[(size_t)o * ER + j] = f2bf(expB[(size_t)j * D_OUT + o]);
}

// ---- gating: P[m,0:128]=xV^T, P[m,128:256]=xU^T, P[m,256:384]=lora_down ----
__global__ void gate_kernel(const float* __restrict__ P, const float* __restrict__ rW,
                            ushort* __restrict__ wtd) {
  int token = blockIdx.x * 4 + (threadIdx.x >> 6);
  int l = threadIdx.x & 63;
  const float* p = P + (size_t)token * CATN;
  float v0 = tanhf(p[l]);
  float v1 = tanhf(p[l + 64]);
  float u0 = 1.f / (1.f + __expf(-p[D_ATT + l]));
  float u1 = 1.f / (1.f + __expf(-p[D_ATT + l + 64]));
  float g0 = v0 * u0, g1 = v1 * u1;
  float rw[8];
  #pragma unroll
  for (int e = 0; e < 8; ++e) {
    float s = g0 * rW[e * D_ATT + l] + g1 * rW[e * D_ATT + l + 64];
    #pragma unroll
    for (int off = 32; off > 0; off >>= 1) s += __shfl_xor(s, off);
    rw[e] = 1.f / (1.f + __expf(-s));
  }
  int q = l >> 4;  // expert index within half (static-select to avoid scratch)
  float rw_a = (q == 0) ? rw[0] : (q == 1) ? rw[1] : (q == 2) ? rw[2] : rw[3];
  float rw_b = (q == 0) ? rw[4] : (q == 1) ? rw[5] : (q == 2) ? rw[6] : rw[7];
  wtd[(size_t)token * ER + l]      = f2bf(p[2 * D_ATT + l]      * rw_a);
  wtd[(size_t)token * ER + l + 64] = f2bf(p[2 * D_ATT + l + 64] * rw_b);
}

// ---- B^T GEMM: C[M,Ncols] = A[M,K] @ Bm[Ncols,K]^T (+bias) (+MoE K-ext) ----
// m97 structure: 128x128 tile, BK=64, 4 waves (2x2), 4x4 16x16x32 frags/wave,
// global_load_lds width-16 staging, 2 barriers per K-step.
template<int MOE, int HASBIAS>
__global__ __launch_bounds__(256, 2)
void gemm_bt_kernel(const ushort* __restrict__ A, const ushort* __restrict__ Bm,
                    float* __restrict__ C, int M, int Ncols, int K,
                    const float* __restrict__ bias,
                    const ushort* __restrict__ Amoe, const ushort* __restrict__ Bmoe)
{
  __shared__ ushort As[128 * 64];
  __shared__ ushort Bs[128 * 64];
  const int tid = threadIdx.x;
  const int w = tid >> 6, l = tid & 63;
  const int wr = w >> 1, wc = w & 1;
  const int l16 = l & 15, lq = l >> 4;
  const int brow = blockIdx.y * 128;
  const int bcol = blockIdx.x * 128;

  f32x4 acc[4][4] = {};

  const int nk_main = K >> 6;
  const int nk_tot = nk_main + (MOE ? (ER >> 6) : 0);

  for (int kt = 0; kt < nk_tot; ++kt) {
    const ushort* a_src; const ushort* b_src; int lda, ldb, k0;
    if (!MOE || kt < nk_main) { a_src = A; b_src = Bm; lda = K; ldb = K; k0 = kt << 6; }
    else { a_src = Amoe; b_src = Bmoe; lda = ER; ldb = ER; k0 = (kt - nk_main) << 6; }

    // stage 128x64 A-tile and B-tile: each wave 4 chunks of 8 rows, 1KB/call
    #pragma unroll
    for (int c = 0; c < 4; ++c) {
      int rloc = w * 32 + c * 8;
      int rl = rloc + (l >> 3);
      int kk = k0 + (l & 7) * 8;
      const ushort* ga = a_src + (size_t)(brow + rl) * lda + kk;
      const ushort* gb = b_src + (size_t)(bcol + rl) * ldb + kk;
      __builtin_amdgcn_global_load_lds((const __attribute__((address_space(1))) void*)ga,
                                       (__attribute__((address_space(3))) void*)(As + rloc * 64),
                                       16, 0, 0);
      __builtin_amdgcn_global_load_lds((const __attribute__((address_space(1))) void*)gb,
                                       (__attribute__((address_space(3))) void*)(Bs + rloc * 64),
                                       16, 0, 0);
    }
    __syncthreads();

    #pragma unroll
    for (int ks = 0; ks < 2; ++ks) {
      bf16x8 af[4], bfv[4];
      #pragma unroll
      for (int mi = 0; mi < 4; ++mi)
        af[mi] = *reinterpret_cast<const bf16x8*>(As + (wr * 64 + mi * 16 + l16) * 64 + ks * 32 + lq * 8);
      #pragma unroll
      for (int ni = 0; ni < 4; ++ni)
        bfv[ni] = *reinterpret_cast<const bf16x8*>(Bs + (wc * 64 + ni * 16 + l16) * 64 + ks * 32 + lq * 8);
      #pragma unroll
      for (int mi = 0; mi < 4; ++mi)
        #pragma unroll
        for (int ni = 0; ni < 4; ++ni)
          acc[mi][ni] = __builtin_amdgcn_mfma_f32_16x16x32_bf16(af[mi], bfv[ni], acc[mi][ni], 0, 0, 0);
    }
    __syncthreads();
  }

  // epilogue: C/D layout col=l&15, row=(l>>4)*4+j (m89-verified)
  #pragma unroll
  for (int ni = 0; ni < 4; ++ni) {
    int col = bcol + wc * 64 + ni * 16 + l16;
    float bs = HASBIAS ? bias[col] : 0.f;
    #pragma unroll
    for (int mi = 0; mi < 4; ++mi) {
      f32x4 v = acc[mi][ni];
      int row0 = brow + wr * 64 + mi * 16 + lq * 4;
      #pragma unroll
      for (int j = 0; j < 4; ++j)
        C[(size_t)(row0 + j) * Ncols + col] = v[j] + bs;
    }
  }
}

extern "C" void kernel_launch(void* const* d_in, const int* in_sizes, int n_in,
                              void* d_out, int out_size, void* d_ws, size_t ws_size,
                              hipStream_t stream) {
  const float* x      = (const float*)d_in[0];
  const float* weight = (const float*)d_in[1];
  const float* bias   = (const float*)d_in[2];
  const float* rV     = (const float*)d_in[3];
  const float* rU     = (const float*)d_in[4];
  const float* rW     = (const float*)d_in[5];
  const float* expA   = (const float*)d_in[6];
  const float* expB   = (const float*)d_in[7];
  float* out = (float*)d_out;

  // workspace layout (all 16B-aligned): ~114 MB total
  ushort* xb  = (ushort*)d_ws;                       // 8192*4096 bf16
  ushort* wb  = xb  + (size_t)M_TOT * D_IN;          // 4096*4096 bf16
  ushort* cat = wb  + (size_t)D_OUT * D_IN;          // 384*4096 bf16
  ushort* bt  = cat + (size_t)CATN * D_IN;           // 4096*128 bf16
  ushort* wtd = bt  + (size_t)D_OUT * ER;            // 8192*128 bf16
  float*  P   = (float*)(wtd + (size_t)M_TOT * ER);  // 8192*384 fp32

  long n4;
  n4 = (long)M_TOT * D_IN / 4;
  f2bf4_kernel<<<dim3((n4 + 255) / 256), 256, 0, stream>>>(x, xb, n4);
  n4 = (long)D_OUT * D_IN / 4;
  f2bf4_kernel<<<dim3((n4 + 255) / 256), 256, 0, stream>>>(weight, wb, n4);
  n4 = (long)D_ATT * D_IN / 4;
  f2bf4_kernel<<<dim3((n4 + 255) / 256), 256, 0, stream>>>(rV, cat, n4);
  f2bf4_kernel<<<dim3((n4 + 255) / 256), 256, 0, stream>>>(rU, cat + (size_t)D_ATT * D_IN, n4);
  prep_catA_kernel<<<dim3(ER * D_IN / 256), 256, 0, stream>>>(expA, cat);
  prep_bt_kernel<<<dim3(ER * D_OUT / 256), 256, 0, stream>>>(expB, bt);

  // P = x @ Cat^T   [8192, 384]
  gemm_bt_kernel<0, 0><<<dim3(CATN / 128, M_TOT / 128), 256, 0, stream>>>(
      xb, cat, P, M_TOT, CATN, D_IN, nullptr, nullptr, nullptr);

  gate_kernel<<<dim3(M_TOT / 4), 256, 0, stream>>>(P, rW, wtd);

  // out = x @ W^T + bias + weighted @ Bt^T   [8192, 4096]
  gemm_bt_kernel<1, 1><<<dim3(D_OUT / 128, M_TOT / 128), 256, 0, stream>>>(
      xb, wb, out, M_TOT, D_OUT, D_IN, bias, wtd, bt);
}

// Round 2
// 428.607 us; speedup vs baseline: 1.0610x; 1.0610x over previous
//
#include <hip/hip_runtime.h>
#include <hip/hip_bf16.h>

// Problem constants
#define M_TOT   8192      // B*N tokens
#define D_IN    4096
#define D_OUT   4096
#define N_E     8
#define N_R     16
#define D_ATT   128
#define ER      128       // N_E*N_R
#define CATN    384       // 2*D_ATT + ER
#define KEXT    4224      // D_IN + ER (padded K for unified GEMM)

typedef __attribute__((ext_vector_type(8))) __bf16 bf16x8;
typedef __attribute__((ext_vector_type(4))) float  f32x4;

__device__ __forceinline__ ushort f2bf(float f) {
  union { float f; unsigned u; } v; v.f = f;
  unsigned r = (v.u + 0x7fffu + ((v.u >> 16) & 1u)) >> 16;
  return (ushort)r;
}

// ---- fp32 -> bf16, contiguous dest ----
__global__ void f2bf4_kernel(const float* __restrict__ in, ushort* __restrict__ out, long n4) {
  long i = blockIdx.x * (long)blockDim.x + threadIdx.x;
  if (i >= n4) return;
  const float4 a = reinterpret_cast<const float4*>(in)[i];
  ushort4 r; r.x = f2bf(a.x); r.y = f2bf(a.y); r.z = f2bf(a.z); r.w = f2bf(a.w);
  reinterpret_cast<ushort4*>(out)[i] = r;
}

// ---- fp32 [rows][4096] -> bf16 [rows][KEXT] (strided dest) ----
__global__ void f2bf4s_kernel(const float* __restrict__ in, ushort* __restrict__ out, long n4) {
  long i = blockIdx.x * (long)blockDim.x + threadIdx.x;
  if (i >= n4) return;
  const float4 a = reinterpret_cast<const float4*>(in)[i];
  ushort4 r; r.x = f2bf(a.x); r.y = f2bf(a.y); r.z = f2bf(a.z); r.w = f2bf(a.w);
  long row = i >> 10, c4 = (i & 1023) << 2;
  *reinterpret_cast<ushort4*>(out + row * KEXT + c4) = r;
}

// ---- Cat rows 256..383: Cat[256+j][d] = experts_A[e][d][r], j=e*16+r ----
__global__ void prep_catA_kernel(const float* __restrict__ expA, ushort* __restrict__ cat) {
  int idx = blockIdx.x * 256 + threadIdx.x;       // over 128*4096
  int j = idx >> 12, d = idx & 4095;
  int e = j >> 4, r = j & 15;
  cat[(size_t)(2 * D_ATT + j) * D_IN + d] = f2bf(expA[((size_t)e * D_IN + d) * N_R + r]);
}

// ---- w_ext cols 4096..4223: w_ext[o][4096+j] = experts_B_flat[j][o] ----
__global__ void prep_bt_kernel(const float* __restrict__ expB, ushort* __restrict__ we) {
  int idx = blockIdx.x * 256 + threadIdx.x;       // over 128*4096
  int j = idx >> 12, o = idx & 4095;              // coalesced read of expB row j
  we[(size_t)o * KEXT + D_IN + j] = f2bf(expB[(size_t)j * D_OUT + o]);
}

// ---- gating: P[m,0:128]=xV^T, P[m,128:256]=xU^T, P[m,256:384]=lora_down ----
// writes weighted lora-down into x_ext cols 4096..4223 (stride KEXT)
__global__ void gate_kernel(const float* __restrict__ P, const float* __restrict__ rW,
                            ushort* __restrict__ wtd) {
  int token = blockIdx.x * 4 + (threadIdx.x >> 6);
  int l = threadIdx.x & 63;
  const float* p = P + (size_t)token * CATN;
  float v0 = tanhf(p[l]);
  float v1 = tanhf(p[l + 64]);
  float u0 = 1.f / (1.f + __expf(-p[D_ATT + l]));
  float u1 = 1.f / (1.f + __expf(-p[D_ATT + l + 64]));
  float g0 = v0 * u0, g1 = v1 * u1;
  float rw[8];
  #pragma unroll
  for (int e = 0; e < 8; ++e) {
    float s = g0 * rW[e * D_ATT + l] + g1 * rW[e * D_ATT + l + 64];
    #pragma unroll
    for (int off = 32; off > 0; off >>= 1) s += __shfl_xor(s, off);
    rw[e] = 1.f / (1.f + __expf(-s));
  }
  int q = l >> 4;  // expert index within half (static-select to avoid scratch)
  float rw_a = (q == 0) ? rw[0] : (q == 1) ? rw[1] : (q == 2) ? rw[2] : rw[3];
  float rw_b = (q == 0) ? rw[4] : (q == 1) ? rw[5] : (q == 2) ? rw[6] : rw[7];
  wtd[(size_t)token * KEXT + l]      = f2bf(p[2 * D_ATT + l]      * rw_a);
  wtd[(size_t)token * KEXT + l + 64] = f2bf(p[2 * D_ATT + l + 64] * rw_b);
}

// ---- 128^2 m97-structure GEMM (used for the small router GEMM only) ----
__global__ __launch_bounds__(256, 2)
void gemm128_kernel(const ushort* __restrict__ A, const ushort* __restrict__ Bm,
                    float* __restrict__ C, int Ncols, int K, int lda, int ldb)
{
  __shared__ ushort As[128 * 64];
  __shared__ ushort Bs[128 * 64];
  const int tid = threadIdx.x;
  const int w = tid >> 6, l = tid & 63;
  const int wr = w >> 1, wc = w & 1;
  const int l16 = l & 15, lq = l >> 4;
  const int brow = blockIdx.y * 128;
  const int bcol = blockIdx.x * 128;

  f32x4 acc[4][4] = {};
  const int nk = K >> 6;

  for (int kt = 0; kt < nk; ++kt) {
    int k0 = kt << 6;
    #pragma unroll
    for (int c = 0; c < 4; ++c) {
      int rloc = w * 32 + c * 8;
      int rl = rloc + (l >> 3);
      int kk = k0 + (l & 7) * 8;
      const ushort* ga = A  + (size_t)(brow + rl) * lda + kk;
      const ushort* gb = Bm + (size_t)(bcol + rl) * ldb + kk;
      __builtin_amdgcn_global_load_lds((const __attribute__((address_space(1))) void*)ga,
                                       (__attribute__((address_space(3))) void*)(As + rloc * 64),
                                       16, 0, 0);
      __builtin_amdgcn_global_load_lds((const __attribute__((address_space(1))) void*)gb,
                                       (__attribute__((address_space(3))) void*)(Bs + rloc * 64),
                                       16, 0, 0);
    }
    __syncthreads();

    #pragma unroll
    for (int ks = 0; ks < 2; ++ks) {
      bf16x8 af[4], bfv[4];
      #pragma unroll
      for (int mi = 0; mi < 4; ++mi)
        af[mi] = *reinterpret_cast<const bf16x8*>(As + (wr * 64 + mi * 16 + l16) * 64 + ks * 32 + lq * 8);
      #pragma unroll
      for (int ni = 0; ni < 4; ++ni)
        bfv[ni] = *reinterpret_cast<const bf16x8*>(Bs + (wc * 64 + ni * 16 + l16) * 64 + ks * 32 + lq * 8);
      #pragma unroll
      for (int mi = 0; mi < 4; ++mi)
        #pragma unroll
        for (int ni = 0; ni < 4; ++ni)
          acc[mi][ni] = __builtin_amdgcn_mfma_f32_16x16x32_bf16(af[mi], bfv[ni], acc[mi][ni], 0, 0, 0);
    }
    __syncthreads();
  }

  #pragma unroll
  for (int ni = 0; ni < 4; ++ni) {
    int col = bcol + wc * 64 + ni * 16 + l16;
    #pragma unroll
    for (int mi = 0; mi < 4; ++mi) {
      f32x4 v = acc[mi][ni];
      int row0 = brow + wr * 64 + mi * 16 + lq * 4;
      #pragma unroll
      for (int j = 0; j < 4; ++j)
        C[(size_t)(row0 + j) * Ncols + col] = v[j];
    }
  }
}

// ---- 256^2 8-phase GEMM (T1+T2+T3+T4+T5), C = A[M,K] @ Bm[N,K]^T + bias ----
// 8 waves (2M x 4N), BK=64, double-buffered LDS (128 KiB), st_16x32 swizzle.
// Per K-tile t: P1{read A-lo + B-lo, stage Ah0(t+1)}, P2{read B-hi, stage Ah1(t+1)},
// P3{read A-hi, stage Bh0(t+2)}, P4{stage Bh1(t+2), vmcnt(4)}. Counted vmcnt: the
// 2 newest halves (Bh(t+2)) stay in flight across the K-tile boundary.
__global__ __launch_bounds__(512, 2)
void gemm256_kernel(const ushort* __restrict__ A, const ushort* __restrict__ Bm,
                    float* __restrict__ C, const float* __restrict__ bias,
                    int Ncols, int K, int ld, int ntm)
{
  __shared__ ushort lds[2][2][2][8192];   // [buf][mat 0=A 1=B][half][128*64]
  const int tid = threadIdx.x;
  const int wid = tid >> 6, l = tid & 63;
  const int wr = wid >> 2, wc = wid & 3;
  const int l16 = l & 15, lq = l >> 4;
  const int exor = ((l16 >> 2) & 1) << 4;      // st_16x32 read-side element XOR

  // XCD-aware bijective swizzle (grid % 8 == 0), N-major: 2 weight panels/XCD
  const int cpx = gridDim.x >> 3;
  const int sid = ((int)blockIdx.x & 7) * cpx + ((int)blockIdx.x >> 3);
  const int brow = (sid % ntm) * 256;
  const int bcol = (sid / ntm) * 256;

  const int NT = K >> 6;

  // staging constants: linear LDS dest, inverse-swizzled global source (rule 21)
  const int srow = tid >> 3;
  const int scol = ((tid & 7) << 3) ^ (((tid >> 5) & 1) << 4);

#define STAGE(buf_, mat_, half_, kt_) do {                                        \
    const ushort* _s = (mat_) ? Bm : A;                                           \
    int _rb = ((mat_) ? bcol : brow) + (half_) * 128 + srow;                      \
    ushort* _d = &lds[(buf_)][(mat_)][(half_)][wid * 512];                        \
    _Pragma("unroll")                                                             \
    for (int _c = 0; _c < 2; ++_c) {                                              \
      const ushort* _g = _s + (size_t)(_rb + _c * 64) * ld + (kt_) * 64 + scol;   \
      __builtin_amdgcn_global_load_lds(                                           \
          (const __attribute__((address_space(1))) void*)_g,                      \
          (__attribute__((address_space(3))) void*)(_d + _c * 4096), 16, 0, 0);   \
    } } while (0)

#define LDA_FRAG(buf_, mi_, ks_) \
  (*reinterpret_cast<const bf16x8*>(&lds[(buf_)][0][wr][((mi_) * 16 + l16) * 64 + (((ks_) * 32 + lq * 8) ^ exor)]))
#define LDB_FRAG(buf_, ni_, ks_) \
  (*reinterpret_cast<const bf16x8*>(&lds[(buf_)][1][wc >> 1][((wc & 1) * 64 + (ni_) * 16 + l16) * 64 + (((ks_) * 32 + lq * 8) ^ exor)]))

  f32x4 acc[8][4] = {};

  // prologue: tile 0 complete + Bh(1); leave Bh(1) in flight (matches steady state)
  STAGE(0, 0, 0, 0); STAGE(0, 0, 1, 0);
  STAGE(0, 1, 0, 0); STAGE(0, 1, 1, 0);
  {
    const int k1 = (NT > 1) ? 1 : 0;
    STAGE(1, 1, 0, k1); STAGE(1, 1, 1, k1);
  }
  asm volatile("s_waitcnt vmcnt(4)" ::: "memory");
  __builtin_amdgcn_s_barrier();

  for (int t = 0; t < NT; ++t) {
    const int buf = t & 1;
    const int ktA = (t + 1 < NT) ? t + 1 : NT - 1;
    const int ktB = (t + 2 < NT) ? t + 2 : NT - 1;
    bf16x8 af[4][2], b0[2][2], b1[2][2];

    // ---- P1: read A mi0-3 + B ni0-1; stage Ah0(t+1) ----
    #pragma unroll
    for (int mi = 0; mi < 4; ++mi)
      #pragma unroll
      for (int ks = 0; ks < 2; ++ks)
        af[mi][ks] = LDA_FRAG(buf, mi, ks);
    #pragma unroll
    for (int ni = 0; ni < 2; ++ni)
      #pragma unroll
      for (int ks = 0; ks < 2; ++ks)
        b0[ni][ks] = LDB_FRAG(buf, ni, ks);
    STAGE(buf ^ 1, 0, 0, ktA);
    __builtin_amdgcn_s_barrier();
    asm volatile("s_waitcnt lgkmcnt(0)" ::: "memory");
    __builtin_amdgcn_s_setprio(1);
    #pragma unroll
    for (int mi = 0; mi < 4; ++mi)
      #pragma unroll
      for (int ni = 0; ni < 2; ++ni)
        #pragma unroll
        for (int ks = 0; ks < 2; ++ks)
          acc[mi][ni] = __builtin_amdgcn_mfma_f32_16x16x32_bf16(af[mi][ks], b0[ni][ks], acc[mi][ni], 0, 0, 0);
    __builtin_amdgcn_s_setprio(0);
    __builtin_amdgcn_s_barrier();

    // ---- P2: read B ni2-3; stage Ah1(t+1) ----
    #pragma unroll
    for (int ni = 0; ni < 2; ++ni)
      #pragma unroll
      for (int ks = 0; ks < 2; ++ks)
        b1[ni][ks] = LDB_FRAG(buf, ni + 2, ks);
    STAGE(buf ^ 1, 0, 1, ktA);
    __builtin_amdgcn_s_barrier();
    asm volatile("s_waitcnt lgkmcnt(0)" ::: "memory");
    __builtin_amdgcn_s_setprio(1);
    #pragma unroll
    for (int mi = 0; mi < 4; ++mi)
      #pragma unroll
      for (int ni = 0; ni < 2; ++ni)
        #pragma unroll
        for (int ks = 0; ks < 2; ++ks)
          acc[mi][ni + 2] = __builtin_amdgcn_mfma_f32_16x16x32_bf16(af[mi][ks], b1[ni][ks], acc[mi][ni + 2], 0, 0, 0);
    __builtin_amdgcn_s_setprio(0);
    __builtin_amdgcn_s_barrier();

    // ---- P3: read A mi4-7 (reuse af); stage Bh0(t+2) into current buf ----
    #pragma unroll
    for (int mi = 0; mi < 4; ++mi)
      #pragma unroll
      for (int ks = 0; ks < 2; ++ks)
        af[mi][ks] = LDA_FRAG(buf, mi + 4, ks);
    STAGE(buf, 1, 0, ktB);
    __builtin_amdgcn_s_barrier();
    asm volatile("s_waitcnt lgkmcnt(0)" ::: "memory");
    __builtin_amdgcn_s_setprio(1);
    #pragma unroll
    for (int mi = 0; mi < 4; ++mi)
      #pragma unroll
      for (int ni = 0; ni < 2; ++ni)
        #pragma unroll
        for (int ks = 0; ks < 2; ++ks)
          acc[mi + 4][ni + 2] = __builtin_amdgcn_mfma_f32_16x16x32_bf16(af[mi][ks], b1[ni][ks], acc[mi + 4][ni + 2], 0, 0, 0);
    __builtin_amdgcn_s_setprio(0);
    __builtin_amdgcn_s_barrier();

    // ---- P4: stage Bh1(t+2); counted vmcnt(4) (Bh(t+2) stays in flight) ----
    STAGE(buf, 1, 1, ktB);
    asm volatile("s_waitcnt vmcnt(4)" ::: "memory");
    __builtin_amdgcn_s_barrier();
    __builtin_amdgcn_s_setprio(1);
    #pragma unroll
    for (int mi = 0; mi < 4; ++mi)
      #pragma unroll
      for (int ni = 0; ni < 2; ++ni)
        #pragma unroll
        for (int ks = 0; ks < 2; ++ks)
          acc[mi + 4][ni] = __builtin_amdgcn_mfma_f32_16x16x32_bf16(af[mi][ks], b0[ni][ks], acc[mi + 4][ni], 0, 0, 0);
    __builtin_amdgcn_s_setprio(0);
    __builtin_amdgcn_s_barrier();
  }

  // drain trailing (harmless) stages before LDS goes out of scope at wave exit
  asm volatile("s_waitcnt vmcnt(0)" ::: "memory");

  // epilogue: C/D layout col=l&15, row=(l>>4)*4+j (m89-verified)
  #pragma unroll
  for (int ni = 0; ni < 4; ++ni) {
    int col = bcol + wc * 64 + ni * 16 + l16;
    float bs = bias[col];
    #pragma unroll
    for (int mi = 0; mi < 8; ++mi) {
      int row0 = brow + wr * 128 + mi * 16 + lq * 4;
      #pragma unroll
      for (int j = 0; j < 4; ++j)
        C[(size_t)(row0 + j) * Ncols + col] = acc[mi][ni][j] + bs;
    }
  }
#undef STAGE
#undef LDA_FRAG
#undef LDB_FRAG
}

extern "C" void kernel_launch(void* const* d_in, const int* in_sizes, int n_in,
                              void* d_out, int out_size, void* d_ws, size_t ws_size,
                              hipStream_t stream) {
  const float* x      = (const float*)d_in[0];
  const float* weight = (const float*)d_in[1];
  const float* bias   = (const float*)d_in[2];
  const float* rV     = (const float*)d_in[3];
  const float* rU     = (const float*)d_in[4];
  const float* rW     = (const float*)d_in[5];
  const float* expA   = (const float*)d_in[6];
  const float* expB   = (const float*)d_in[7];
  float* out = (float*)d_out;

  // workspace: x_ext[8192][4224], w_ext[4096][4224], cat[384][4096], P[8192][384]
  ushort* xe  = (ushort*)d_ws;
  ushort* we  = xe  + (size_t)M_TOT * KEXT;
  ushort* cat = we  + (size_t)D_OUT * KEXT;
  float*  P   = (float*)(cat + (size_t)CATN * D_IN);

  long n4;
  n4 = (long)M_TOT * D_IN / 4;
  f2bf4s_kernel<<<dim3((n4 + 255) / 256), 256, 0, stream>>>(x, xe, n4);
  n4 = (long)D_OUT * D_IN / 4;
  f2bf4s_kernel<<<dim3((n4 + 255) / 256), 256, 0, stream>>>(weight, we, n4);
  n4 = (long)D_ATT * D_IN / 4;
  f2bf4_kernel<<<dim3((n4 + 255) / 256), 256, 0, stream>>>(rV, cat, n4);
  f2bf4_kernel<<<dim3((n4 + 255) / 256), 256, 0, stream>>>(rU, cat + (size_t)D_ATT * D_IN, n4);
  prep_catA_kernel<<<dim3(ER * D_IN / 256), 256, 0, stream>>>(expA, cat);
  prep_bt_kernel<<<dim3(ER * D_OUT / 256), 256, 0, stream>>>(expB, we);

  // P = x @ Cat^T   [8192, 384]
  gemm128_kernel<<<dim3(CATN / 128, M_TOT / 128), 256, 0, stream>>>(
      xe, cat, P, CATN, D_IN, KEXT, D_IN);

  // weighted lora-down -> x_ext cols 4096..4223
  gate_kernel<<<dim3(M_TOT / 4), 256, 0, stream>>>(P, rW, xe + D_IN);

  // out = x_ext @ w_ext^T + bias   [8192, 4096], K = 4224
  gemm256_kernel<<<dim3((D_OUT / 256) * (M_TOT / 256)), 512, 0, stream>>>(
      xe, we, out, bias, D_OUT, KEXT, KEXT, M_TOT / 256);
}

// Round 3
// 405.114 us; speedup vs baseline: 1.1225x; 1.0580x over previous
//
#include <hip/hip_runtime.h>
#include <hip/hip_bf16.h>

// Problem constants
#define M_TOT   8192      // B*N tokens
#define D_IN    4096
#define D_OUT   4096
#define N_E     8
#define N_R     16
#define D_ATT   128
#define ER      128       // N_E*N_R
#define CATN    384       // 2*D_ATT + ER
#define KEXT    4224      // D_IN + ER (padded K for unified GEMM)

typedef __attribute__((ext_vector_type(8))) __bf16 bf16x8;
typedef __attribute__((ext_vector_type(4))) float  f32x4;

__device__ __forceinline__ ushort f2bf(float f) {
  union { float f; unsigned u; } v; v.f = f;
  unsigned r = (v.u + 0x7fffu + ((v.u >> 16) & 1u)) >> 16;
  return (ushort)r;
}

// ---- fp32 -> bf16, contiguous dest ----
__global__ void f2bf4_kernel(const float* __restrict__ in, ushort* __restrict__ out, long n4) {
  long i = blockIdx.x * (long)blockDim.x + threadIdx.x;
  if (i >= n4) return;
  const float4 a = reinterpret_cast<const float4*>(in)[i];
  ushort4 r; r.x = f2bf(a.x); r.y = f2bf(a.y); r.z = f2bf(a.z); r.w = f2bf(a.w);
  reinterpret_cast<ushort4*>(out)[i] = r;
}

// ---- fp32 [rows][4096] -> bf16 [rows][KEXT] (strided dest) ----
__global__ void f2bf4s_kernel(const float* __restrict__ in, ushort* __restrict__ out, long n4) {
  long i = blockIdx.x * (long)blockDim.x + threadIdx.x;
  if (i >= n4) return;
  const float4 a = reinterpret_cast<const float4*>(in)[i];
  ushort4 r; r.x = f2bf(a.x); r.y = f2bf(a.y); r.z = f2bf(a.z); r.w = f2bf(a.w);
  long row = i >> 10, c4 = (i & 1023) << 2;
  *reinterpret_cast<ushort4*>(out + row * KEXT + c4) = r;
}

// ---- Cat rows 256..383: Cat[256+j][d] = experts_A[e][d][r], j=e*16+r ----
__global__ void prep_catA_kernel(const float* __restrict__ expA, ushort* __restrict__ cat) {
  int idx = blockIdx.x * 256 + threadIdx.x;       // over 128*4096
  int j = idx >> 12, d = idx & 4095;
  int e = j >> 4, r = j & 15;
  cat[(size_t)(2 * D_ATT + j) * D_IN + d] = f2bf(expA[((size_t)e * D_IN + d) * N_R + r]);
}

// ---- w_ext cols 4096..4223: w_ext[o][4096+j] = experts_B_flat[j][o] ----
__global__ void prep_bt_kernel(const float* __restrict__ expB, ushort* __restrict__ we) {
  int idx = blockIdx.x * 256 + threadIdx.x;       // over 128*4096
  int j = idx >> 12, o = idx & 4095;              // coalesced read of expB row j
  we[(size_t)o * KEXT + D_IN + j] = f2bf(expB[(size_t)j * D_OUT + o]);
}

// ---- gating: P[m,0:128]=xV^T, P[m,128:256]=xU^T, P[m,256:384]=lora_down ----
// writes weighted lora-down into x_ext cols 4096..4223 (stride KEXT)
__global__ void gate_kernel(const float* __restrict__ P, const float* __restrict__ rW,
                            ushort* __restrict__ wtd) {
  int token = blockIdx.x * 4 + (threadIdx.x >> 6);
  int l = threadIdx.x & 63;
  const float* p = P + (size_t)token * CATN;
  float v0 = tanhf(p[l]);
  float v1 = tanhf(p[l + 64]);
  float u0 = 1.f / (1.f + __expf(-p[D_ATT + l]));
  float u1 = 1.f / (1.f + __expf(-p[D_ATT + l + 64]));
  float g0 = v0 * u0, g1 = v1 * u1;
  float rw[8];
  #pragma unroll
  for (int e = 0; e < 8; ++e) {
    float s = g0 * rW[e * D_ATT + l] + g1 * rW[e * D_ATT + l + 64];
    #pragma unroll
    for (int off = 32; off > 0; off >>= 1) s += __shfl_xor(s, off);
    rw[e] = 1.f / (1.f + __expf(-s));
  }
  int q = l >> 4;  // expert index within half (static-select to avoid scratch)
  float rw_a = (q == 0) ? rw[0] : (q == 1) ? rw[1] : (q == 2) ? rw[2] : rw[3];
  float rw_b = (q == 0) ? rw[4] : (q == 1) ? rw[5] : (q == 2) ? rw[6] : rw[7];
  wtd[(size_t)token * KEXT + l]      = f2bf(p[2 * D_ATT + l]      * rw_a);
  wtd[(size_t)token * KEXT + l + 64] = f2bf(p[2 * D_ATT + l + 64] * rw_b);
}

// ---- 128^2 m97-structure GEMM (used for the small router GEMM only) ----
__global__ __launch_bounds__(256, 2)
void gemm128_kernel(const ushort* __restrict__ A, const ushort* __restrict__ Bm,
                    float* __restrict__ C, int Ncols, int K, int lda, int ldb)
{
  __shared__ ushort As[128 * 64];
  __shared__ ushort Bs[128 * 64];
  const int tid = threadIdx.x;
  const int w = tid >> 6, l = tid & 63;
  const int wr = w >> 1, wc = w & 1;
  const int l16 = l & 15, lq = l >> 4;
  const int brow = blockIdx.y * 128;
  const int bcol = blockIdx.x * 128;

  f32x4 acc[4][4] = {};
  const int nk = K >> 6;

  for (int kt = 0; kt < nk; ++kt) {
    int k0 = kt << 6;
    #pragma unroll
    for (int c = 0; c < 4; ++c) {
      int rloc = w * 32 + c * 8;
      int rl = rloc + (l >> 3);
      int kk = k0 + (l & 7) * 8;
      const ushort* ga = A  + (size_t)(brow + rl) * lda + kk;
      const ushort* gb = Bm + (size_t)(bcol + rl) * ldb + kk;
      __builtin_amdgcn_global_load_lds((const __attribute__((address_space(1))) void*)ga,
                                       (__attribute__((address_space(3))) void*)(As + rloc * 64),
                                       16, 0, 0);
      __builtin_amdgcn_global_load_lds((const __attribute__((address_space(1))) void*)gb,
                                       (__attribute__((address_space(3))) void*)(Bs + rloc * 64),
                                       16, 0, 0);
    }
    __syncthreads();

    #pragma unroll
    for (int ks = 0; ks < 2; ++ks) {
      bf16x8 af[4], bfv[4];
      #pragma unroll
      for (int mi = 0; mi < 4; ++mi)
        af[mi] = *reinterpret_cast<const bf16x8*>(As + (wr * 64 + mi * 16 + l16) * 64 + ks * 32 + lq * 8);
      #pragma unroll
      for (int ni = 0; ni < 4; ++ni)
        bfv[ni] = *reinterpret_cast<const bf16x8*>(Bs + (wc * 64 + ni * 16 + l16) * 64 + ks * 32 + lq * 8);
      #pragma unroll
      for (int mi = 0; mi < 4; ++mi)
        #pragma unroll
        for (int ni = 0; ni < 4; ++ni)
          acc[mi][ni] = __builtin_amdgcn_mfma_f32_16x16x32_bf16(af[mi], bfv[ni], acc[mi][ni], 0, 0, 0);
    }
    __syncthreads();
  }

  #pragma unroll
  for (int ni = 0; ni < 4; ++ni) {
    int col = bcol + wc * 64 + ni * 16 + l16;
    #pragma unroll
    for (int mi = 0; mi < 4; ++mi) {
      f32x4 v = acc[mi][ni];
      int row0 = brow + wr * 64 + mi * 16 + lq * 4;
      #pragma unroll
      for (int j = 0; j < 4; ++j)
        C[(size_t)(row0 + j) * Ncols + col] = v[j];
    }
  }
}

// ---- 256^2 8-phase GEMM (T1+T2+T3+T4+T5), C = A[M,K] @ Bm[N,K]^T + bias ----
// 8 waves (2M x 4N), BK=64, double-buffered LDS (128 KiB).
// LDS swizzle (full 3-bit, layout [128][64] bf16, row stride = 128B = 1 bank
// sweep so the row must feed the bank bits): elem' = elem ^ ((row&7)<<3).
// ds_read_b128 cluster = (ks<<2|lq) ^ (l16&7) -> uniform 8 lanes/cluster.
// Write side (rule 21): linear LDS dest + inverse-swizzled GLOBAL source col.
__global__ __launch_bounds__(512, 2)
void gemm256_kernel(const ushort* __restrict__ A, const ushort* __restrict__ Bm,
                    float* __restrict__ C, const float* __restrict__ bias,
                    int Ncols, int K, int ld, int ntm)
{
  __shared__ ushort lds[2][2][2][8192];   // [buf][mat 0=A 1=B][half][128*64]
  const int tid = threadIdx.x;
  const int wid = tid >> 6, l = tid & 63;
  const int wr = wid >> 2, wc = wid & 3;
  const int l16 = l & 15, lq = l >> 4;
  const int rxor = (l16 & 7) << 3;             // read-side elem XOR (row&7)<<3

  // XCD-aware bijective swizzle (grid % 8 == 0), N-major: 2 weight panels/XCD
  const int cpx = gridDim.x >> 3;
  const int sid = ((int)blockIdx.x & 7) * cpx + ((int)blockIdx.x >> 3);
  const int brow = (sid % ntm) * 256;
  const int bcol = (sid / ntm) * 256;

  const int NT = K >> 6;

  // staging: linear LDS dest; global source col pre-swizzled by dest row&7
  const int srow = tid >> 3;
  const int scol = (((tid & 7) ^ ((tid >> 3) & 7)) << 3);

#define STAGE(buf_, mat_, half_, kt_) do {                                        \
    const ushort* _s = (mat_) ? Bm : A;                                           \
    int _rb = ((mat_) ? bcol : brow) + (half_) * 128 + srow;                      \
    ushort* _d = &lds[(buf_)][(mat_)][(half_)][wid * 512];                        \
    _Pragma("unroll")                                                             \
    for (int _c = 0; _c < 2; ++_c) {                                              \
      const ushort* _g = _s + (size_t)(_rb + _c * 64) * ld + (kt_) * 64 + scol;   \
      __builtin_amdgcn_global_load_lds(                                           \
          (const __attribute__((address_space(1))) void*)_g,                      \
          (__attribute__((address_space(3))) void*)(_d + _c * 4096), 16, 0, 0);   \
    } } while (0)

#define LDA_FRAG(buf_, mi_, ks_) \
  (*reinterpret_cast<const bf16x8*>(&lds[(buf_)][0][wr][((mi_) * 16 + l16) * 64 + (((ks_) * 32 + lq * 8) ^ rxor)]))
#define LDB_FRAG(buf_, ni_, ks_) \
  (*reinterpret_cast<const bf16x8*>(&lds[(buf_)][1][wc >> 1][((wc & 1) * 64 + (ni_) * 16 + l16) * 64 + (((ks_) * 32 + lq * 8) ^ rxor)]))

  f32x4 acc[8][4] = {};

  // prologue: tile 0 complete + Bh(1); leave Bh(1) in flight (matches steady state)
  STAGE(0, 0, 0, 0); STAGE(0, 0, 1, 0);
  STAGE(0, 1, 0, 0); STAGE(0, 1, 1, 0);
  {
    const int k1 = (NT > 1) ? 1 : 0;
    STAGE(1, 1, 0, k1); STAGE(1, 1, 1, k1);
  }
  asm volatile("s_waitcnt vmcnt(4)" ::: "memory");
  __builtin_amdgcn_s_barrier();

  for (int t = 0; t < NT; ++t) {
    const int buf = t & 1;
    const int ktA = (t + 1 < NT) ? t + 1 : NT - 1;
    const int ktB = (t + 2 < NT) ? t + 2 : NT - 1;
    bf16x8 af[4][2], b0[2][2], b1[2][2];

    // ---- P1: read A mi0-3 + B ni0-1; stage Ah0(t+1) ----
    #pragma unroll
    for (int mi = 0; mi < 4; ++mi)
      #pragma unroll
      for (int ks = 0; ks < 2; ++ks)
        af[mi][ks] = LDA_FRAG(buf, mi, ks);
    #pragma unroll
    for (int ni = 0; ni < 2; ++ni)
      #pragma unroll
      for (int ks = 0; ks < 2; ++ks)
        b0[ni][ks] = LDB_FRAG(buf, ni, ks);
    STAGE(buf ^ 1, 0, 0, ktA);
    __builtin_amdgcn_s_barrier();
    asm volatile("s_waitcnt lgkmcnt(0)" ::: "memory");
    __builtin_amdgcn_s_setprio(1);
    #pragma unroll
    for (int mi = 0; mi < 4; ++mi)
      #pragma unroll
      for (int ni = 0; ni < 2; ++ni)
        #pragma unroll
        for (int ks = 0; ks < 2; ++ks)
          acc[mi][ni] = __builtin_amdgcn_mfma_f32_16x16x32_bf16(af[mi][ks], b0[ni][ks], acc[mi][ni], 0, 0, 0);
    __builtin_amdgcn_s_setprio(0);
    __builtin_amdgcn_s_barrier();

    // ---- P2: read B ni2-3; stage Ah1(t+1) ----
    #pragma unroll
    for (int ni = 0; ni < 2; ++ni)
      #pragma unroll
      for (int ks = 0; ks < 2; ++ks)
        b1[ni][ks] = LDB_FRAG(buf, ni + 2, ks);
    STAGE(buf ^ 1, 0, 1, ktA);
    __builtin_amdgcn_s_barrier();
    asm volatile("s_waitcnt lgkmcnt(0)" ::: "memory");
    __builtin_amdgcn_s_setprio(1);
    #pragma unroll
    for (int mi = 0; mi < 4; ++mi)
      #pragma unroll
      for (int ni = 0; ni < 2; ++ni)
        #pragma unroll
        for (int ks = 0; ks < 2; ++ks)
          acc[mi][ni + 2] = __builtin_amdgcn_mfma_f32_16x16x32_bf16(af[mi][ks], b1[ni][ks], acc[mi][ni + 2], 0, 0, 0);
    __builtin_amdgcn_s_setprio(0);
    __builtin_amdgcn_s_barrier();

    // ---- P3: read A mi4-7 (reuse af); stage Bh0(t+2) into current buf ----
    #pragma unroll
    for (int mi = 0; mi < 4; ++mi)
      #pragma unroll
      for (int ks = 0; ks < 2; ++ks)
        af[mi][ks] = LDA_FRAG(buf, mi + 4, ks);
    STAGE(buf, 1, 0, ktB);
    __builtin_amdgcn_s_barrier();
    asm volatile("s_waitcnt lgkmcnt(0)" ::: "memory");
    __builtin_amdgcn_s_setprio(1);
    #pragma unroll
    for (int mi = 0; mi < 4; ++mi)
      #pragma unroll
      for (int ni = 0; ni < 2; ++ni)
        #pragma unroll
        for (int ks = 0; ks < 2; ++ks)
          acc[mi + 4][ni + 2] = __builtin_amdgcn_mfma_f32_16x16x32_bf16(af[mi][ks], b1[ni][ks], acc[mi + 4][ni + 2], 0, 0, 0);
    __builtin_amdgcn_s_setprio(0);
    __builtin_amdgcn_s_barrier();

    // ---- P4: stage Bh1(t+2); counted vmcnt(4) (Bh(t+2) stays in flight) ----
    STAGE(buf, 1, 1, ktB);
    asm volatile("s_waitcnt vmcnt(4)" ::: "memory");
    __builtin_amdgcn_s_barrier();
    __builtin_amdgcn_s_setprio(1);
    #pragma unroll
    for (int mi = 0; mi < 4; ++mi)
      #pragma unroll
      for (int ni = 0; ni < 2; ++ni)
        #pragma unroll
        for (int ks = 0; ks < 2; ++ks)
          acc[mi + 4][ni] = __builtin_amdgcn_mfma_f32_16x16x32_bf16(af[mi][ks], b0[ni][ks], acc[mi + 4][ni], 0, 0, 0);
    __builtin_amdgcn_s_setprio(0);
    __builtin_amdgcn_s_barrier();
  }

  // drain trailing (harmless) stages before LDS goes out of scope at wave exit
  asm volatile("s_waitcnt vmcnt(0)" ::: "memory");

  // epilogue: C/D layout col=l&15, row=(l>>4)*4+j (m89-verified)
  #pragma unroll
  for (int ni = 0; ni < 4; ++ni) {
    int col = bcol + wc * 64 + ni * 16 + l16;
    float bs = bias[col];
    #pragma unroll
    for (int mi = 0; mi < 8; ++mi) {
      int row0 = brow + wr * 128 + mi * 16 + lq * 4;
      #pragma unroll
      for (int j = 0; j < 4; ++j)
        C[(size_t)(row0 + j) * Ncols + col] = acc[mi][ni][j] + bs;
    }
  }
#undef STAGE
#undef LDA_FRAG
#undef LDB_FRAG
}

extern "C" void kernel_launch(void* const* d_in, const int* in_sizes, int n_in,
                              void* d_out, int out_size, void* d_ws, size_t ws_size,
                              hipStream_t stream) {
  const float* x      = (const float*)d_in[0];
  const float* weight = (const float*)d_in[1];
  const float* bias   = (const float*)d_in[2];
  const float* rV     = (const float*)d_in[3];
  const float* rU     = (const float*)d_in[4];
  const float* rW     = (const float*)d_in[5];
  const float* expA   = (const float*)d_in[6];
  const float* expB   = (const float*)d_in[7];
  float* out = (float*)d_out;

  // workspace: x_ext[8192][4224], w_ext[4096][4224], cat[384][4096], P[8192][384]
  ushort* xe  = (ushort*)d_ws;
  ushort* we  = xe  + (size_t)M_TOT * KEXT;
  ushort* cat = we  + (size_t)D_OUT * KEXT;
  float*  P   = (float*)(cat + (size_t)CATN * D_IN);

  long n4;
  n4 = (long)M_TOT * D_IN / 4;
  f2bf4s_kernel<<<dim3((n4 + 255) / 256), 256, 0, stream>>>(x, xe, n4);
  n4 = (long)D_OUT * D_IN / 4;
  f2bf4s_kernel<<<dim3((n4 + 255) / 256), 256, 0, stream>>>(weight, we, n4);
  n4 = (long)D_ATT * D_IN / 4;
  f2bf4_kernel<<<dim3((n4 + 255) / 256), 256, 0, stream>>>(rV, cat, n4);
  f2bf4_kernel<<<dim3((n4 + 255) / 256), 256, 0, stream>>>(rU, cat + (size_t)D_ATT * D_IN, n4);
  prep_catA_kernel<<<dim3(ER * D_IN / 256), 256, 0, stream>>>(expA, cat);
  prep_bt_kernel<<<dim3(ER * D_OUT / 256), 256, 0, stream>>>(expB, we);

  // P = x @ Cat^T   [8192, 384]
  gemm128_kernel<<<dim3(CATN / 128, M_TOT / 128), 256, 0, stream>>>(
      xe, cat, P, CATN, D_IN, KEXT, D_IN);

  // weighted lora-down -> x_ext cols 4096..4223
  gate_kernel<<<dim3(M_TOT / 4), 256, 0, stream>>>(P, rW, xe + D_IN);

  // out = x_ext @ w_ext^T + bias   [8192, 4096], K = 4224
  gemm256_kernel<<<dim3((D_OUT / 256) * (M_TOT / 256)), 512, 0, stream>>>(
      xe, we, out, bias, D_OUT, KEXT, KEXT, M_TOT / 256);
}

// Round 4
// 401.436 us; speedup vs baseline: 1.1328x; 1.0092x over previous
//
#include <hip/hip_runtime.h>
#include <hip/hip_bf16.h>

// Problem constants
#define M_TOT   8192      // B*N tokens
#define D_IN    4096
#define D_OUT   4096
#define N_E     8
#define N_R     16
#define D_ATT   128
#define ER      128       // N_E*N_R
#define CATN    384       // 2*D_ATT + ER
#define KEXT    4224      // D_IN + ER (padded K for unified GEMM)
#define NTK     66        // KEXT/64 K-tiles (even)
#define NTM     32        // M_TOT/256

typedef __attribute__((ext_vector_type(8))) __bf16 bf16x8;
typedef __attribute__((ext_vector_type(4))) float  f32x4;

__device__ __forceinline__ ushort f2bf(float f) {
  union { float f; unsigned u; } v; v.f = f;
  unsigned r = (v.u + 0x7fffu + ((v.u >> 16) & 1u)) >> 16;
  return (ushort)r;
}

// ---- fp32 -> bf16, contiguous dest ----
__global__ void f2bf4_kernel(const float* __restrict__ in, ushort* __restrict__ out, long n4) {
  long i = blockIdx.x * (long)blockDim.x + threadIdx.x;
  if (i >= n4) return;
  const float4 a = reinterpret_cast<const float4*>(in)[i];
  ushort4 r; r.x = f2bf(a.x); r.y = f2bf(a.y); r.z = f2bf(a.z); r.w = f2bf(a.w);
  reinterpret_cast<ushort4*>(out)[i] = r;
}

// ---- fp32 [rows][4096] -> bf16 [rows][KEXT] (strided dest) ----
__global__ void f2bf4s_kernel(const float* __restrict__ in, ushort* __restrict__ out, long n4) {
  long i = blockIdx.x * (long)blockDim.x + threadIdx.x;
  if (i >= n4) return;
  const float4 a = reinterpret_cast<const float4*>(in)[i];
  ushort4 r; r.x = f2bf(a.x); r.y = f2bf(a.y); r.z = f2bf(a.z); r.w = f2bf(a.w);
  long row = i >> 10, c4 = (i & 1023) << 2;
  *reinterpret_cast<ushort4*>(out + row * KEXT + c4) = r;
}

// ---- Cat rows 256..383: Cat[256+j][d] = experts_A[e][d][r], j=e*16+r ----
__global__ void prep_catA_kernel(const float* __restrict__ expA, ushort* __restrict__ cat) {
  int idx = blockIdx.x * 256 + threadIdx.x;       // over 128*4096
  int j = idx >> 12, d = idx & 4095;
  int e = j >> 4, r = j & 15;
  cat[(size_t)(2 * D_ATT + j) * D_IN + d] = f2bf(expA[((size_t)e * D_IN + d) * N_R + r]);
}

// ---- w_ext cols 4096..4223: w_ext[o][4096+j] = experts_B_flat[j][o] ----
__global__ void prep_bt_kernel(const float* __restrict__ expB, ushort* __restrict__ we) {
  int idx = blockIdx.x * 256 + threadIdx.x;       // over 128*4096
  int j = idx >> 12, o = idx & 4095;              // coalesced read of expB row j
  we[(size_t)o * KEXT + D_IN + j] = f2bf(expB[(size_t)j * D_OUT + o]);
}

// ---- gating: P[m,0:128]=xV^T, P[m,128:256]=xU^T, P[m,256:384]=lora_down ----
// writes weighted lora-down into x_ext cols 4096..4223 (stride KEXT)
__global__ void gate_kernel(const float* __restrict__ P, const float* __restrict__ rW,
                            ushort* __restrict__ wtd) {
  int token = blockIdx.x * 4 + (threadIdx.x >> 6);
  int l = threadIdx.x & 63;
  const float* p = P + (size_t)token * CATN;
  float v0 = tanhf(p[l]);
  float v1 = tanhf(p[l + 64]);
  float u0 = 1.f / (1.f + __expf(-p[D_ATT + l]));
  float u1 = 1.f / (1.f + __expf(-p[D_ATT + l + 64]));
  float g0 = v0 * u0, g1 = v1 * u1;
  float rw[8];
  #pragma unroll
  for (int e = 0; e < 8; ++e) {
    float s = g0 * rW[e * D_ATT + l] + g1 * rW[e * D_ATT + l + 64];
    #pragma unroll
    for (int off = 32; off > 0; off >>= 1) s += __shfl_xor(s, off);
    rw[e] = 1.f / (1.f + __expf(-s));
  }
  int q = l >> 4;  // expert index within half (static-select to avoid scratch)
  float rw_a = (q == 0) ? rw[0] : (q == 1) ? rw[1] : (q == 2) ? rw[2] : rw[3];
  float rw_b = (q == 0) ? rw[4] : (q == 1) ? rw[5] : (q == 2) ? rw[6] : rw[7];
  wtd[(size_t)token * KEXT + l]      = f2bf(p[2 * D_ATT + l]      * rw_a);
  wtd[(size_t)token * KEXT + l + 64] = f2bf(p[2 * D_ATT + l + 64] * rw_b);
}

// ---- 128^2 m97-structure GEMM: P = x_ext[:, :4096] @ cat^T (compile-time dims) ----
__global__ __launch_bounds__(256, 2)
void gemm128_kernel(const ushort* __restrict__ A, const ushort* __restrict__ Bm,
                    float* __restrict__ C)
{
  __shared__ ushort As[128 * 64];
  __shared__ ushort Bs[128 * 64];
  const int tid = threadIdx.x;
  const int w = tid >> 6, l = tid & 63;
  const int wr = w >> 1, wc = w & 1;
  const int l16 = l & 15, lq = l >> 4;
  const int brow = blockIdx.y * 128;
  const int bcol = blockIdx.x * 128;

  f32x4 acc[4][4] = {};

  for (int kt = 0; kt < (D_IN >> 6); ++kt) {
    int k0 = kt << 6;
    #pragma unroll
    for (int c = 0; c < 4; ++c) {
      int rloc = w * 32 + c * 8;
      int rl = rloc + (l >> 3);
      int kk = k0 + (l & 7) * 8;
      const ushort* ga = A  + (size_t)(brow + rl) * KEXT + kk;
      const ushort* gb = Bm + (size_t)(bcol + rl) * D_IN + kk;
      __builtin_amdgcn_global_load_lds((const __attribute__((address_space(1))) void*)ga,
                                       (__attribute__((address_space(3))) void*)(As + rloc * 64),
                                       16, 0, 0);
      __builtin_amdgcn_global_load_lds((const __attribute__((address_space(1))) void*)gb,
                                       (__attribute__((address_space(3))) void*)(Bs + rloc * 64),
                                       16, 0, 0);
    }
    __syncthreads();

    #pragma unroll
    for (int ks = 0; ks < 2; ++ks) {
      bf16x8 af[4], bfv[4];
      #pragma unroll
      for (int mi = 0; mi < 4; ++mi)
        af[mi] = *reinterpret_cast<const bf16x8*>(As + (wr * 64 + mi * 16 + l16) * 64 + ks * 32 + lq * 8);
      #pragma unroll
      for (int ni = 0; ni < 4; ++ni)
        bfv[ni] = *reinterpret_cast<const bf16x8*>(Bs + (wc * 64 + ni * 16 + l16) * 64 + ks * 32 + lq * 8);
      #pragma unroll
      for (int mi = 0; mi < 4; ++mi)
        #pragma unroll
        for (int ni = 0; ni < 4; ++ni)
          acc[mi][ni] = __builtin_amdgcn_mfma_f32_16x16x32_bf16(af[mi], bfv[ni], acc[mi][ni], 0, 0, 0);
    }
    __syncthreads();
  }

  #pragma unroll
  for (int ni = 0; ni < 4; ++ni) {
    int col = bcol + wc * 64 + ni * 16 + l16;
    #pragma unroll
    for (int mi = 0; mi < 4; ++mi) {
      f32x4 v = acc[mi][ni];
      int row0 = brow + wr * 64 + mi * 16 + lq * 4;
      #pragma unroll
      for (int j = 0; j < 4; ++j)
        C[(size_t)(row0 + j) * CATN + col] = v[j];
    }
  }
}

// ---- 256^2 8-phase GEMM with READ ROTATION: out = x_ext @ w_ext^T + bias ----
// 8 waves (2M x 4N), BK=64, double-buffered LDS (128 KiB), full 3-bit swizzle.
// Each phase's ds_reads are issued inside the PREVIOUS phase's MFMA window
// (after its barrier+lgkmcnt(0), at prio 1), so LDS-read latency hides under
// the matrix pipe and each lgkmcnt(0) finds its data already resident.
// Per tile t (buf=t&1):
//  P1: stage Ah0(t+1); bar; lgkm0[waits R1 from prev P4]; {rd B-hi | MFMA AloxBlo}; bar
//  P2: stage Ah1(t+1); bar; lgkm0[waits B-hi];           {rd A-hi | MFMA AloxBhi}; bar
//  P3: stage Bh0(t+2); bar; lgkm0[waits A-hi];           {        MFMA AhixBhi}; bar
//  P4: stage Bh1(t+2); vmcnt(4); bar;                    {rd R1(t+1) | MFMA AhixBlo}; bar
// vmcnt(4) leaves only Bh(t+2) in flight; A(t+1)/B(t+1) proven landed for R1.
__global__ __launch_bounds__(512, 2)
void gemm256_kernel(const ushort* __restrict__ A, const ushort* __restrict__ Bm,
                    float* __restrict__ C, const float* __restrict__ bias)
{
  __shared__ ushort lds[2][2][2][8192];   // [buf][mat 0=A 1=B][half][128*64]
  const int tid = threadIdx.x;
  const int wid = tid >> 6, l = tid & 63;
  const int wr = wid >> 2, wc = wid & 3;
  const int l16 = l & 15, lq = l >> 4;
  const int rxor = (l16 & 7) << 3;             // read-side elem XOR (row&7)<<3

  // XCD-aware bijective swizzle (512 % 8 == 0), N-major: weight panels stay in L2
  const int cpx = (NTM * (D_OUT / 256)) >> 3;
  const int sid = ((int)blockIdx.x & 7) * cpx + ((int)blockIdx.x >> 3);
  const int brow = (sid % NTM) * 256;
  const int bcol = (sid / NTM) * 256;

  // staging: linear LDS dest; global source col pre-swizzled by dest row&7
  const int srow = tid >> 3;
  const int scol = (((tid & 7) ^ ((tid >> 3) & 7)) << 3);

#define STAGE(buf_, mat_, half_, kt_) do {                                        \
    const ushort* _s = (mat_) ? Bm : A;                                           \
    int _rb = ((mat_) ? bcol : brow) + (half_) * 128 + srow;                      \
    ushort* _d = &lds[(buf_)][(mat_)][(half_)][wid * 512];                        \
    _Pragma("unroll")                                                             \
    for (int _c = 0; _c < 2; ++_c) {                                              \
      const ushort* _g = _s + (size_t)(_rb + _c * 64) * KEXT + (kt_) * 64 + scol; \
      __builtin_amdgcn_global_load_lds(                                           \
          (const __attribute__((address_space(1))) void*)_g,                      \
          (__attribute__((address_space(3))) void*)(_d + _c * 4096), 16, 0, 0);   \
    } } while (0)

#define LDA_FRAG(buf_, mi_, ks_) \
  (*reinterpret_cast<const bf16x8*>(&lds[(buf_)][0][wr][((mi_) * 16 + l16) * 64 + (((ks_) * 32 + lq * 8) ^ rxor)]))
#define LDB_FRAG(buf_, ni_, ks_) \
  (*reinterpret_cast<const bf16x8*>(&lds[(buf_)][1][wc >> 1][((wc & 1) * 64 + (ni_) * 16 + l16) * 64 + (((ks_) * 32 + lq * 8) ^ rxor)]))

#define RD_ALO(buf_, dst_) \
    _Pragma("unroll") for (int mi = 0; mi < 4; ++mi) \
      _Pragma("unroll") for (int ks = 0; ks < 2; ++ks) dst_[mi][ks] = LDA_FRAG(buf_, mi, ks);
#define RD_BLO(buf_, dst_) \
    _Pragma("unroll") for (int ni = 0; ni < 2; ++ni) \
      _Pragma("unroll") for (int ks = 0; ks < 2; ++ks) dst_[ni][ks] = LDB_FRAG(buf_, ni, ks);

#define MFMA_Q(accm0_, accn0_, a_, b_) \
    _Pragma("unroll") for (int mi = 0; mi < 4; ++mi) \
      _Pragma("unroll") for (int ni = 0; ni < 2; ++ni) \
        _Pragma("unroll") for (int ks = 0; ks < 2; ++ks) \
          acc[(accm0_) + mi][(accn0_) + ni] = __builtin_amdgcn_mfma_f32_16x16x32_bf16( \
              a_[mi][ks], b_[ni][ks], acc[(accm0_) + mi][(accn0_) + ni], 0, 0, 0);

#define TILE(t_, buf_, aIn_, b0In_, aOut_, b0Out_) do {                           \
    bf16x8 b1[2][2], aHi[4][2];                                                   \
    const int ktA = ((t_) + 1 < NTK) ? (t_) + 1 : NTK - 1;                        \
    const int ktB = ((t_) + 2 < NTK) ? (t_) + 2 : NTK - 1;                        \
    /* P1 */                                                                      \
    STAGE(buf_ ^ 1, 0, 0, ktA);                                                   \
    __builtin_amdgcn_s_barrier();                                                 \
    asm volatile("s_waitcnt lgkmcnt(0)" ::: "memory");                            \
    __builtin_amdgcn_s_setprio(1);                                                \
    _Pragma("unroll") for (int ni = 0; ni < 2; ++ni)                              \
      _Pragma("unroll") for (int ks = 0; ks < 2; ++ks)                            \
        b1[ni][ks] = LDB_FRAG(buf_, ni + 2, ks);                                  \
    MFMA_Q(0, 0, aIn_, b0In_);                                                    \
    __builtin_amdgcn_s_setprio(0);                                                \
    __builtin_amdgcn_s_barrier();                                                 \
    /* P2 */                                                                      \
    STAGE(buf_ ^ 1, 0, 1, ktA);                                                   \
    __builtin_amdgcn_s_barrier();                                                 \
    asm volatile("s_waitcnt lgkmcnt(0)" ::: "memory");                            \
    __builtin_amdgcn_s_setprio(1);                                                \
    _Pragma("unroll") for (int mi = 0; mi < 4; ++mi)                              \
      _Pragma("unroll") for (int ks = 0; ks < 2; ++ks)                            \
        aHi[mi][ks] = LDA_FRAG(buf_, mi + 4, ks);                                 \
    MFMA_Q(0, 2, aIn_, b1);                                                       \
    __builtin_amdgcn_s_setprio(0);                                                \
    __builtin_amdgcn_s_barrier();                                                 \
    /* P3 */                                                                      \
    STAGE(buf_, 1, 0, ktB);                                                       \
    __builtin_amdgcn_s_barrier();                                                 \
    asm volatile("s_waitcnt lgkmcnt(0)" ::: "memory");                            \
    __builtin_amdgcn_s_setprio(1);                                                \
    MFMA_Q(4, 2, aHi, b1);                                                        \
    __builtin_amdgcn_s_setprio(0);                                                \
    __builtin_amdgcn_s_barrier();                                                 \
    /* P4 */                                                                      \
    STAGE(buf_, 1, 1, ktB);                                                       \
    asm volatile("s_waitcnt vmcnt(4)" ::: "memory");                              \
    __builtin_amdgcn_s_barrier();                                                 \
    __builtin_amdgcn_s_setprio(1);                                                \
    RD_ALO(buf_ ^ 1, aOut_);                                                      \
    RD_BLO(buf_ ^ 1, b0Out_);                                                     \
    MFMA_Q(4, 0, aHi, b0In_);                                                     \
    __builtin_amdgcn_s_setprio(0);                                                \
    __builtin_amdgcn_s_barrier();                                                 \
  } while (0)

  f32x4 acc[8][4] = {};
  bf16x8 aA[4][2], b0A[2][2], aB[4][2], b0B[2][2];

  // prologue: tile 0 complete + B(1); leave B(1) in flight, then pre-read R1(0)
  STAGE(0, 0, 0, 0); STAGE(0, 0, 1, 0);
  STAGE(0, 1, 0, 0); STAGE(0, 1, 1, 0);
  STAGE(1, 1, 0, 1); STAGE(1, 1, 1, 1);
  asm volatile("s_waitcnt vmcnt(4)" ::: "memory");
  __builtin_amdgcn_s_barrier();
  RD_ALO(0, aA);
  RD_BLO(0, b0A);

  #pragma unroll 1
  for (int tp = 0; tp < NTK / 2; ++tp) {
    TILE(2 * tp,     0, aA, b0A, aB, b0B);
    TILE(2 * tp + 1, 1, aB, b0B, aA, b0A);
  }

  asm volatile("s_waitcnt vmcnt(0) lgkmcnt(0)" ::: "memory");

  // epilogue: C/D layout col=l&15, row=(l>>4)*4+j (m89-verified)
  #pragma unroll
  for (int ni = 0; ni < 4; ++ni) {
    int col = bcol + wc * 64 + ni * 16 + l16;
    float bs = bias[col];
    #pragma unroll
    for (int mi = 0; mi < 8; ++mi) {
      int row0 = brow + wr * 128 + mi * 16 + lq * 4;
      #pragma unroll
      for (int j = 0; j < 4; ++j)
        C[(size_t)(row0 + j) * D_OUT + col] = acc[mi][ni][j] + bs;
    }
  }
#undef STAGE
#undef LDA_FRAG
#undef LDB_FRAG
#undef RD_ALO
#undef RD_BLO
#undef MFMA_Q
#undef TILE
}

extern "C" void kernel_launch(void* const* d_in, const int* in_sizes, int n_in,
                              void* d_out, int out_size, void* d_ws, size_t ws_size,
                              hipStream_t stream) {
  const float* x      = (const float*)d_in[0];
  const float* weight = (const float*)d_in[1];
  const float* bias   = (const float*)d_in[2];
  const float* rV     = (const float*)d_in[3];
  const float* rU     = (const float*)d_in[4];
  const float* rW     = (const float*)d_in[5];
  const float* expA   = (const float*)d_in[6];
  const float* expB   = (const float*)d_in[7];
  float* out = (float*)d_out;

  // workspace: x_ext[8192][4224], w_ext[4096][4224], cat[384][4096], P[8192][384]
  ushort* xe  = (ushort*)d_ws;
  ushort* we  = xe  + (size_t)M_TOT * KEXT;
  ushort* cat = we  + (size_t)D_OUT * KEXT;
  float*  P   = (float*)(cat + (size_t)CATN * D_IN);

  long n4;
  n4 = (long)M_TOT * D_IN / 4;
  f2bf4s_kernel<<<dim3((n4 + 255) / 256), 256, 0, stream>>>(x, xe, n4);
  n4 = (long)D_OUT * D_IN / 4;
  f2bf4s_kernel<<<dim3((n4 + 255) / 256), 256, 0, stream>>>(weight, we, n4);
  n4 = (long)D_ATT * D_IN / 4;
  f2bf4_kernel<<<dim3((n4 + 255) / 256), 256, 0, stream>>>(rV, cat, n4);
  f2bf4_kernel<<<dim3((n4 + 255) / 256), 256, 0, stream>>>(rU, cat + (size_t)D_ATT * D_IN, n4);
  prep_catA_kernel<<<dim3(ER * D_IN / 256), 256, 0, stream>>>(expA, cat);
  prep_bt_kernel<<<dim3(ER * D_OUT / 256), 256, 0, stream>>>(expB, we);

  // P = x @ Cat^T   [8192, 384]
  gemm128_kernel<<<dim3(CATN / 128, M_TOT / 128), 256, 0, stream>>>(xe, cat, P);

  // weighted lora-down -> x_ext cols 4096..4223
  gate_kernel<<<dim3(M_TOT / 4), 256, 0, stream>>>(P, rW, xe + D_IN);

  // out = x_ext @ w_ext^T + bias   [8192, 4096], K = 4224
  gemm256_kernel<<<dim3((D_OUT / 256) * (M_TOT / 256)), 512, 0, stream>>>(xe, we, out, bias);
}